// Round 1
// baseline (1363.258 us; speedup 1.0000x reference)
//
#include <hip/hip_runtime.h>

#define N_NODES 100000
#define N_EDGES 1600000
#define D 128
#define SCAN_CHUNK 1024
#define SCAN_BLOCKS ((N_NODES + SCAN_CHUNK - 1) / SCAN_CHUNK)  // 98

// ---------------- CSR build ----------------

__global__ void hist_kernel(const int* __restrict__ row, int* __restrict__ counts) {
    int e = blockIdx.x * blockDim.x + threadIdx.x;
    if (e < N_EDGES) atomicAdd(&counts[row[e]], 1);
}

__global__ void scan_reduce(const int* __restrict__ counts, int* __restrict__ bsums) {
    int b = blockIdx.x, t = threadIdx.x;
    int base = b * SCAN_CHUNK + t * 4;
    int s = 0;
#pragma unroll
    for (int i = 0; i < 4; ++i) {
        int idx = base + i;
        if (idx < N_NODES) s += counts[idx];
    }
    __shared__ int red[256];
    red[t] = s;
    __syncthreads();
    for (int d = 128; d > 0; d >>= 1) {
        if (t < d) red[t] += red[t + d];
        __syncthreads();
    }
    if (t == 0) bsums[b] = red[0];
}

__global__ void scan_top(int* __restrict__ bsums, int nb, int* __restrict__ offsets) {
    __shared__ int s[256];
    int t = threadIdx.x;
    int v = (t < nb) ? bsums[t] : 0;
    s[t] = v;
    __syncthreads();
    for (int d = 1; d < 256; d <<= 1) {
        int x = (t >= d) ? s[t - d] : 0;
        __syncthreads();
        s[t] += x;
        __syncthreads();
    }
    if (t < nb) bsums[t] = s[t] - v;  // exclusive
    if (t == 0) offsets[N_NODES] = N_EDGES;
}

__global__ void scan_apply(const int* __restrict__ counts, const int* __restrict__ bsums,
                           int* __restrict__ offsets) {
    int b = blockIdx.x, t = threadIdx.x;
    int base = b * SCAN_CHUNK + t * 4;
    int c[4];
    int s = 0;
#pragma unroll
    for (int i = 0; i < 4; ++i) {
        int idx = base + i;
        c[i] = (idx < N_NODES) ? counts[idx] : 0;
        s += c[i];
    }
    __shared__ int sc[256];
    int mine = s;
    sc[t] = s;
    __syncthreads();
    for (int d = 1; d < 256; d <<= 1) {
        int x = (t >= d) ? sc[t - d] : 0;
        __syncthreads();
        sc[t] += x;
        __syncthreads();
    }
    int run = sc[t] - mine + bsums[b];
#pragma unroll
    for (int i = 0; i < 4; ++i) {
        int idx = base + i;
        if (idx < N_NODES) offsets[idx] = run;
        run += c[i];
    }
}

__global__ void scatter_kernel(const int* __restrict__ row, const int* __restrict__ col,
                               const float* __restrict__ val, const int* __restrict__ offsets,
                               int* __restrict__ cursor, int* __restrict__ scol,
                               float* __restrict__ sval) {
    int e = blockIdx.x * blockDim.x + threadIdx.x;
    if (e >= N_EDGES) return;
    int r = row[e];
    int p = offsets[r] + atomicAdd(&cursor[r], 1);
    scol[p] = col[e];
    sval[p] = val[e];
}

// ---------------- SpMM: one wave per row, lane = float2 slice ----------------
// out[r] = features[r] + sum_j sval[j] * features[scol[j]]   (EPSILON = 0)

__global__ __launch_bounds__(256) void spmm_kernel(
    const int* __restrict__ scol, const float* __restrict__ sval,
    const int* __restrict__ offsets, const float* __restrict__ feat,
    float* __restrict__ out) {
    int wid = (blockIdx.x * blockDim.x + threadIdx.x) >> 6;
    int lane = threadIdx.x & 63;
    if (wid >= N_NODES) return;
    int r = wid;
    int beg = offsets[r], end = offsets[r + 1];
    const float2* f2 = (const float2*)feat;
    float2 acc = f2[r * 64 + lane];
    for (int j = beg; j < end; ++j) {
        int c = scol[j];
        float v = sval[j];
        float2 f = f2[c * 64 + lane];
        acc.x += v * f.x;
        acc.y += v * f.y;
    }
    ((float2*)out)[r * 64 + lane] = acc;
}

// ---------------- GEMM 128x128, in-place on X ----------------
// X[N,128] = act(X @ W + b).  W staged in LDS (64 KB). Block 256 = 4 waves;
// wave ty handles 8 rows; lane tx computes cols tx and tx+64.
// In-place safe: each block's rows disjoint; each thread reads only its own
// rows into registers before writing.

template <int DO_RELU>
__global__ __launch_bounds__(256) void gemm128(float* __restrict__ X,
                                               const float* __restrict__ W,
                                               const float* __restrict__ bias, int nrows) {
    __shared__ float Ws[128 * 128];
    {
        const float4* W4 = (const float4*)W;
        float4* Ws4 = (float4*)Ws;
        for (int i = threadIdx.x; i < 4096; i += 256) Ws4[i] = W4[i];
    }
    __syncthreads();
    int tx = threadIdx.x & 63;
    int ty = threadIdx.x >> 6;
    float b0 = bias[tx];
    float b1v = bias[tx + 64];
    int nchunks = nrows / 32;  // 100000/32 = 3125 exact
    for (int chunk = blockIdx.x; chunk < nchunks; chunk += gridDim.x) {
        int row0 = chunk * 32 + ty * 8;
        float acc[8][2];
#pragma unroll
        for (int r = 0; r < 8; ++r) acc[r][0] = acc[r][1] = 0.f;
        for (int kc = 0; kc < 128; kc += 4) {
            float4 a[8];
#pragma unroll
            for (int r = 0; r < 8; ++r)
                a[r] = *(const float4*)&X[(size_t)(row0 + r) * D + kc];
#pragma unroll
            for (int kk = 0; kk < 4; ++kk) {
                float w0 = Ws[(kc + kk) * 128 + tx];
                float w1 = Ws[(kc + kk) * 128 + tx + 64];
#pragma unroll
                for (int r = 0; r < 8; ++r) {
                    float av = (kk == 0) ? a[r].x : (kk == 1) ? a[r].y : (kk == 2) ? a[r].z : a[r].w;
                    acc[r][0] += av * w0;
                    acc[r][1] += av * w1;
                }
            }
        }
#pragma unroll
        for (int r = 0; r < 8; ++r) {
            float v0 = acc[r][0] + b0;
            float v1 = acc[r][1] + b1v;
            if (DO_RELU) {
                v0 = fmaxf(v0, 0.f);
                v1 = fmaxf(v1, 0.f);
            }
            X[(size_t)(row0 + r) * D + tx] = v0;
            X[(size_t)(row0 + r) * D + tx + 64] = v1;
        }
    }
}

extern "C" void kernel_launch(void* const* d_in, const int* in_sizes, int n_in,
                              void* d_out, int out_size, void* d_ws, size_t ws_size,
                              hipStream_t stream) {
    const int* indices = (const int*)d_in[0];      // [2, E]
    const float* values = (const float*)d_in[1];   // [E]
    const float* features = (const float*)d_in[2]; // [N, 128]
    const float* W1 = (const float*)d_in[3];
    const float* b1 = (const float*)d_in[4];
    const float* W2 = (const float*)d_in[5];
    const float* b2 = (const float*)d_in[6];
    float* out = (float*)d_out;

    const int* row = indices;
    const int* col = indices + N_EDGES;

    // ws layout (ints): counts[N] | cursor[N] | offsets[N+1] | pad | bsums[256] | scol[E] | sval[E]
    int* wsI = (int*)d_ws;
    int* counts = wsI;
    int* cursor = wsI + N_NODES;
    int* offsets = wsI + 2 * N_NODES;
    int* bsums = wsI + 3 * N_NODES + 8;
    int* scol = wsI + 3 * N_NODES + 8 + 256;
    float* sval = (float*)(scol + N_EDGES);

    // zero counts + cursor (adjacent)
    hipMemsetAsync(counts, 0, 2 * N_NODES * sizeof(int), stream);

    int eb = (N_EDGES + 255) / 256;
    hist_kernel<<<eb, 256, 0, stream>>>(row, counts);
    scan_reduce<<<SCAN_BLOCKS, 256, 0, stream>>>(counts, bsums);
    scan_top<<<1, 256, 0, stream>>>(bsums, SCAN_BLOCKS, offsets);
    scan_apply<<<SCAN_BLOCKS, 256, 0, stream>>>(counts, bsums, offsets);
    scatter_kernel<<<eb, 256, 0, stream>>>(row, col, values, offsets, cursor, scol, sval);

    // SpMM + residual -> d_out (one wave per row)
    int spmm_blocks = (N_NODES * 64 + 255) / 256;  // 25000
    spmm_kernel<<<spmm_blocks, 256, 0, stream>>>(scol, sval, offsets, features, out);

    // GEMM1 (relu) then GEMM2, both in-place on d_out
    gemm128<1><<<512, 256, 0, stream>>>(out, W1, b1, N_NODES);
    gemm128<0><<<512, 256, 0, stream>>>(out, W2, b2, N_NODES);
}

// Round 2
// 572.486 us; speedup vs baseline: 2.3813x; 2.3813x over previous
//
#include <hip/hip_runtime.h>

#define N_NODES 100000
#define N_EDGES 1600000
#define D 128
#define SCAN_CHUNK 1024
#define SCAN_BLOCKS ((N_NODES + SCAN_CHUNK - 1) / SCAN_CHUNK)  // 98

// ---------------- CSR build ----------------

__global__ void hist_kernel(const int* __restrict__ row, int* __restrict__ counts) {
    int e = blockIdx.x * blockDim.x + threadIdx.x;
    if (e < N_EDGES) atomicAdd(&counts[row[e]], 1);
}

__global__ void scan_reduce(const int* __restrict__ counts, int* __restrict__ bsums) {
    int b = blockIdx.x, t = threadIdx.x;
    int base = b * SCAN_CHUNK + t * 4;
    int s = 0;
#pragma unroll
    for (int i = 0; i < 4; ++i) {
        int idx = base + i;
        if (idx < N_NODES) s += counts[idx];
    }
    __shared__ int red[256];
    red[t] = s;
    __syncthreads();
    for (int d = 128; d > 0; d >>= 1) {
        if (t < d) red[t] += red[t + d];
        __syncthreads();
    }
    if (t == 0) bsums[b] = red[0];
}

__global__ void scan_top(int* __restrict__ bsums, int nb, int* __restrict__ offsets) {
    __shared__ int s[256];
    int t = threadIdx.x;
    int v = (t < nb) ? bsums[t] : 0;
    s[t] = v;
    __syncthreads();
    for (int d = 1; d < 256; d <<= 1) {
        int x = (t >= d) ? s[t - d] : 0;
        __syncthreads();
        s[t] += x;
        __syncthreads();
    }
    if (t < nb) bsums[t] = s[t] - v;  // exclusive
    if (t == 0) offsets[N_NODES] = N_EDGES;
}

__global__ void scan_apply(const int* __restrict__ counts, const int* __restrict__ bsums,
                           int* __restrict__ offsets) {
    int b = blockIdx.x, t = threadIdx.x;
    int base = b * SCAN_CHUNK + t * 4;
    int c[4];
    int s = 0;
#pragma unroll
    for (int i = 0; i < 4; ++i) {
        int idx = base + i;
        c[i] = (idx < N_NODES) ? counts[idx] : 0;
        s += c[i];
    }
    __shared__ int sc[256];
    int mine = s;
    sc[t] = s;
    __syncthreads();
    for (int d = 1; d < 256; d <<= 1) {
        int x = (t >= d) ? sc[t - d] : 0;
        __syncthreads();
        sc[t] += x;
        __syncthreads();
    }
    int run = sc[t] - mine + bsums[b];
#pragma unroll
    for (int i = 0; i < 4; ++i) {
        int idx = base + i;
        if (idx < N_NODES) offsets[idx] = run;
        run += c[i];
    }
}

__global__ void scatter_kernel(const int* __restrict__ row, const int* __restrict__ col,
                               const float* __restrict__ val, const int* __restrict__ offsets,
                               int* __restrict__ cursor, int* __restrict__ scol,
                               float* __restrict__ sval) {
    int e = blockIdx.x * blockDim.x + threadIdx.x;
    if (e >= N_EDGES) return;
    int r = row[e];
    int p = offsets[r] + atomicAdd(&cursor[r], 1);
    scol[p] = col[e];
    sval[p] = val[e];
}

// ---------------- SpMM: one wave per row, lane = float2 slice ----------------
// out[r] = features[r] + sum_j sval[j] * features[scol[j]]   (EPSILON = 0)

__global__ __launch_bounds__(256) void spmm_kernel(
    const int* __restrict__ scol, const float* __restrict__ sval,
    const int* __restrict__ offsets, const float* __restrict__ feat,
    float* __restrict__ out) {
    int wid = (blockIdx.x * blockDim.x + threadIdx.x) >> 6;
    int lane = threadIdx.x & 63;
    if (wid >= N_NODES) return;
    int r = wid;
    int beg = offsets[r], end = offsets[r + 1];
    const float2* f2 = (const float2*)feat;
    float2 acc = f2[r * 64 + lane];
    for (int j = beg; j < end; ++j) {
        int c = scol[j];
        float v = sval[j];
        float2 f = f2[c * 64 + lane];
        acc.x += v * f.x;
        acc.y += v * f.y;
    }
    ((float2*)out)[r * 64 + lane] = acc;
}

// ---------------- GEMM v2: 128x128 tile, 8x8 register tile, in-place ----------------
// X[N,128] = act(X @ W + b). Block 256 threads = 16(tx) x 16(ty).
// Per thread: rows ty*8..+7, cols {4tx..4tx+3, 64+4tx..+3}, 8x8 fp32 acc.
// A staged transposed [k][row] (pad 132 -> 2-way max on writes, conflict-free
// b128 reads); W staged [k][col]. LDS = 16.6 KB -> no LDS occupancy cap.
// In-place safe: block reads only its own 128 rows, writes after all reads.

template <int DO_RELU>
__global__ __launch_bounds__(256) void gemm128_v2(float* __restrict__ X,
                                                  const float* __restrict__ W,
                                                  const float* __restrict__ bias, int nrows) {
    __shared__ float As[16][132];
    __shared__ float Ws[16][128];
    int t = threadIdx.x;
    int tx = t & 15;
    int ty = t >> 4;
    int row0 = blockIdx.x * 128;

    float acc[8][8];
#pragma unroll
    for (int r = 0; r < 8; ++r)
#pragma unroll
        for (int c = 0; c < 8; ++c) acc[r][c] = 0.f;

    for (int kc = 0; kc < 128; kc += 16) {
        // stage A: 128 rows x 16 k, transposed into As[k][row]
#pragma unroll
        for (int j = 0; j < 2; ++j) {
            int f = t + 256 * j;
            int r = f >> 2, k4 = (f & 3) << 2;
            int gr = row0 + r;
            float4 v = make_float4(0.f, 0.f, 0.f, 0.f);
            if (gr < nrows) v = *(const float4*)&X[(size_t)gr * D + kc + k4];
            As[k4 + 0][r] = v.x;
            As[k4 + 1][r] = v.y;
            As[k4 + 2][r] = v.z;
            As[k4 + 3][r] = v.w;
        }
        // stage W chunk: 16 k-rows x 128 cols, as-is
#pragma unroll
        for (int j = 0; j < 2; ++j) {
            int f = t + 256 * j;
            int k = f >> 5, c4 = (f & 31) << 2;
            *(float4*)&Ws[k][c4] = *(const float4*)&W[(size_t)(kc + k) * D + c4];
        }
        __syncthreads();
#pragma unroll
        for (int k = 0; k < 16; ++k) {
            float4 a0 = *(float4*)&As[k][ty * 8];
            float4 a1 = *(float4*)&As[k][ty * 8 + 4];
            float4 w0 = *(float4*)&Ws[k][tx * 4];
            float4 w1 = *(float4*)&Ws[k][tx * 4 + 64];
            float a[8] = {a0.x, a0.y, a0.z, a0.w, a1.x, a1.y, a1.z, a1.w};
            float w[8] = {w0.x, w0.y, w0.z, w0.w, w1.x, w1.y, w1.z, w1.w};
#pragma unroll
            for (int r = 0; r < 8; ++r)
#pragma unroll
                for (int c = 0; c < 8; ++c) acc[r][c] += a[r] * w[c];
        }
        __syncthreads();
    }

    float4 bb0 = *(const float4*)&bias[tx * 4];
    float4 bb1 = *(const float4*)&bias[tx * 4 + 64];
    float b[8] = {bb0.x, bb0.y, bb0.z, bb0.w, bb1.x, bb1.y, bb1.z, bb1.w};
#pragma unroll
    for (int r = 0; r < 8; ++r) {
        int gr = row0 + ty * 8 + r;
        if (gr >= nrows) continue;
        float o[8];
#pragma unroll
        for (int c = 0; c < 8; ++c) {
            o[c] = acc[r][c] + b[c];
            if (DO_RELU) o[c] = fmaxf(o[c], 0.f);
        }
        *(float4*)&X[(size_t)gr * D + tx * 4] = make_float4(o[0], o[1], o[2], o[3]);
        *(float4*)&X[(size_t)gr * D + 64 + tx * 4] = make_float4(o[4], o[5], o[6], o[7]);
    }
}

extern "C" void kernel_launch(void* const* d_in, const int* in_sizes, int n_in,
                              void* d_out, int out_size, void* d_ws, size_t ws_size,
                              hipStream_t stream) {
    const int* indices = (const int*)d_in[0];      // [2, E]
    const float* values = (const float*)d_in[1];   // [E]
    const float* features = (const float*)d_in[2]; // [N, 128]
    const float* W1 = (const float*)d_in[3];
    const float* b1 = (const float*)d_in[4];
    const float* W2 = (const float*)d_in[5];
    const float* b2 = (const float*)d_in[6];
    float* out = (float*)d_out;

    const int* row = indices;
    const int* col = indices + N_EDGES;

    // ws layout (ints): counts[N] | cursor[N] | offsets[N+1] | pad | bsums[256] | scol[E] | sval[E]
    int* wsI = (int*)d_ws;
    int* counts = wsI;
    int* cursor = wsI + N_NODES;
    int* offsets = wsI + 2 * N_NODES;
    int* bsums = wsI + 3 * N_NODES + 8;
    int* scol = wsI + 3 * N_NODES + 8 + 256;
    float* sval = (float*)(scol + N_EDGES);

    // zero counts + cursor (adjacent)
    hipMemsetAsync(counts, 0, 2 * N_NODES * sizeof(int), stream);

    int eb = (N_EDGES + 255) / 256;
    hist_kernel<<<eb, 256, 0, stream>>>(row, counts);
    scan_reduce<<<SCAN_BLOCKS, 256, 0, stream>>>(counts, bsums);
    scan_top<<<1, 256, 0, stream>>>(bsums, SCAN_BLOCKS, offsets);
    scan_apply<<<SCAN_BLOCKS, 256, 0, stream>>>(counts, bsums, offsets);
    scatter_kernel<<<eb, 256, 0, stream>>>(row, col, values, offsets, cursor, scol, sval);

    // SpMM + residual -> d_out (one wave per row)
    int spmm_blocks = (N_NODES * 64 + 255) / 256;  // 25000
    spmm_kernel<<<spmm_blocks, 256, 0, stream>>>(scol, sval, offsets, features, out);

    // GEMM1 (relu) then GEMM2, both in-place on d_out
    int gb = (N_NODES + 127) / 128;  // 782
    gemm128_v2<1><<<gb, 256, 0, stream>>>(out, W1, b1, N_NODES);
    gemm128_v2<0><<<gb, 256, 0, stream>>>(out, W2, b2, N_NODES);
}

// Round 3
// 453.928 us; speedup vs baseline: 3.0032x; 1.2612x over previous
//
#include <hip/hip_runtime.h>

#define N_NODES 100000
#define N_EDGES 1600000
#define D 128
#define SCAN_CHUNK 1024
#define SCAN_BLOCKS ((N_NODES + SCAN_CHUNK - 1) / SCAN_CHUNK)  // 98

typedef unsigned short u16;
typedef unsigned int u32;
typedef __attribute__((ext_vector_type(8))) short bf16x8;
typedef __attribute__((ext_vector_type(4))) float f32x4;

__device__ __forceinline__ u16 f2bf(float f) {
    u32 u = __float_as_uint(f);
    u += 0x7fffu + ((u >> 16) & 1u);  // round-to-nearest-even
    return (u16)(u >> 16);
}

// ---------------- bf16 conversions ----------------

// features fp32 [N,128] -> bf16 packed. 8 elems/thread. grid = N*D/8/256 = 6250
__global__ void convert_feat(const float4* __restrict__ f4, uint4* __restrict__ o4) {
    int idx = blockIdx.x * blockDim.x + threadIdx.x;  // [0, N*D/8)
    float4 a = f4[idx * 2], b = f4[idx * 2 + 1];
    uint4 o;
    o.x = (u32)f2bf(a.x) | ((u32)f2bf(a.y) << 16);
    o.y = (u32)f2bf(a.z) | ((u32)f2bf(a.w) << 16);
    o.z = (u32)f2bf(b.x) | ((u32)f2bf(b.y) << 16);
    o.w = (u32)f2bf(b.z) | ((u32)f2bf(b.w) << 16);
    o4[idx] = o;
}

// W[k][n] fp32 -> Wt[n][k] bf16, both 128x128. grid = 2*16384/256 = 128
__global__ void convert_w(const float* __restrict__ W1, const float* __restrict__ W2,
                          u16* __restrict__ W1t, u16* __restrict__ W2t) {
    int flat = blockIdx.x * blockDim.x + threadIdx.x;  // [0, 32768)
    int m = flat >> 14;
    int idx = flat & 16383;
    int n = idx & 127;   // consecutive threads -> consecutive n: coalesced read
    int k = idx >> 7;
    const float* src = m ? W2 : W1;
    u16* dst = m ? W2t : W1t;
    dst[n * 128 + k] = f2bf(src[k * 128 + n]);
}

// ---------------- CSR build ----------------

__global__ void hist_kernel(const int* __restrict__ row, int* __restrict__ counts) {
    int e = blockIdx.x * blockDim.x + threadIdx.x;
    if (e < N_EDGES) atomicAdd(&counts[row[e]], 1);
}

__global__ void scan_reduce(const int* __restrict__ counts, int* __restrict__ bsums) {
    int b = blockIdx.x, t = threadIdx.x;
    int base = b * SCAN_CHUNK + t * 4;
    int s = 0;
#pragma unroll
    for (int i = 0; i < 4; ++i) {
        int idx = base + i;
        if (idx < N_NODES) s += counts[idx];
    }
    __shared__ int red[256];
    red[t] = s;
    __syncthreads();
    for (int d = 128; d > 0; d >>= 1) {
        if (t < d) red[t] += red[t + d];
        __syncthreads();
    }
    if (t == 0) bsums[b] = red[0];
}

__global__ void scan_top(int* __restrict__ bsums, int nb, int* __restrict__ offsets) {
    __shared__ int s[256];
    int t = threadIdx.x;
    int v = (t < nb) ? bsums[t] : 0;
    s[t] = v;
    __syncthreads();
    for (int d = 1; d < 256; d <<= 1) {
        int x = (t >= d) ? s[t - d] : 0;
        __syncthreads();
        s[t] += x;
        __syncthreads();
    }
    if (t < nb) bsums[t] = s[t] - v;  // exclusive
    if (t == 0) offsets[N_NODES] = N_EDGES;
}

__global__ void scan_apply(const int* __restrict__ counts, const int* __restrict__ bsums,
                           int* __restrict__ offsets) {
    int b = blockIdx.x, t = threadIdx.x;
    int base = b * SCAN_CHUNK + t * 4;
    int c[4];
    int s = 0;
#pragma unroll
    for (int i = 0; i < 4; ++i) {
        int idx = base + i;
        c[i] = (idx < N_NODES) ? counts[idx] : 0;
        s += c[i];
    }
    __shared__ int sc[256];
    int mine = s;
    sc[t] = s;
    __syncthreads();
    for (int d = 1; d < 256; d <<= 1) {
        int x = (t >= d) ? sc[t - d] : 0;
        __syncthreads();
        sc[t] += x;
        __syncthreads();
    }
    int run = sc[t] - mine + bsums[b];
#pragma unroll
    for (int i = 0; i < 4; ++i) {
        int idx = base + i;
        if (idx < N_NODES) offsets[idx] = run;
        run += c[i];
    }
}

// packed (col, val) per edge: one 8B store instead of two 4B stores
__global__ void scatter_kernel(const int* __restrict__ row, const int* __restrict__ col,
                               const float* __restrict__ val, const int* __restrict__ offsets,
                               int* __restrict__ cursor, int2* __restrict__ scev) {
    int e = blockIdx.x * blockDim.x + threadIdx.x;
    if (e >= N_EDGES) return;
    int r = row[e];
    int p = offsets[r] + atomicAdd(&cursor[r], 1);
    int2 ev;
    ev.x = col[e];
    ev.y = __float_as_int(val[e]);
    scev[p] = ev;
}

// ---------------- SpMM (bf16 gather): one wave per row ----------------
// Xb[r] = bf16( featb[r] + sum_j v_j * featb[col_j] )

__global__ __launch_bounds__(256) void spmm_bf16(
    const int2* __restrict__ scev, const int* __restrict__ offsets,
    const u32* __restrict__ featb, u32* __restrict__ Xb) {
    int wid = (blockIdx.x * blockDim.x + threadIdx.x) >> 6;
    int lane = threadIdx.x & 63;
    if (wid >= N_NODES) return;
    int beg = offsets[wid], end = offsets[wid + 1];
    u32 self = featb[wid * 64 + lane];
    float accx = __uint_as_float(self << 16);
    float accy = __uint_as_float(self & 0xffff0000u);
    for (int j = beg; j < end; ++j) {
        int2 e = scev[j];
        float v = __int_as_float(e.y);
        u32 p = featb[e.x * 64 + lane];
        accx += v * __uint_as_float(p << 16);
        accy += v * __uint_as_float(p & 0xffff0000u);
    }
    Xb[wid * 64 + lane] = (u32)f2bf(accx) | ((u32)f2bf(accy) << 16);
}

// ---------------- MFMA bf16 GEMM: out = act(X @ W + b) ----------------
// Block 256 = 4 waves; block tile 128 rows; wave tile 32 rows x 128 cols.
// Wt[n][k] staged in LDS (pad 136 -> 2-way conflicts = free).
// A-fragments loaded straight from global (16 rows x 64B: fully coalesced).
// mfma_f32_16x16x32_bf16: A lane=(m=l&15, k=quad*8+j); B lane=(n=l&15, k=quad*8+j);
// D lane: col=l&15, row=quad*4+reg  [guide §3, m89/m91-verified]

template <int RELU, int OUT32>
__global__ __launch_bounds__(256, 2) void gemm_mfma(
    const u16* __restrict__ Xb, const u16* __restrict__ Wt,
    const float* __restrict__ bias, u16* __restrict__ outb, float* __restrict__ outf) {
    __shared__ u16 Ws[128][136];
    int t = threadIdx.x;
    {
        const uint4* wsrc = (const uint4*)Wt;
#pragma unroll
        for (int i = 0; i < 8; ++i) {
            int f = t + 256 * i;  // [0,2048) 16B chunks
            int n = f >> 4;
            int c8 = (f & 15) << 3;
            *(uint4*)&Ws[n][c8] = wsrc[f];
        }
    }
    __syncthreads();

    int w = t >> 6, lane = t & 63;
    int quad = lane >> 4, l16 = lane & 15;
    int row0 = blockIdx.x * 128 + w * 32;

    f32x4 acc[2][8];
#pragma unroll
    for (int rt = 0; rt < 2; ++rt)
#pragma unroll
        for (int ct = 0; ct < 8; ++ct) acc[rt][ct] = (f32x4){0.f, 0.f, 0.f, 0.f};

    int ra = row0 + l16;
    int rb = row0 + 16 + l16;
    if (ra > N_NODES - 1) ra = N_NODES - 1;  // clamp: keeps loads in-bounds,
    if (rb > N_NODES - 1) rb = N_NODES - 1;  // stores are guarded below
    const u16* pa = Xb + (size_t)ra * D + quad * 8;
    const u16* pb = Xb + (size_t)rb * D + quad * 8;

#pragma unroll
    for (int kb = 0; kb < 128; kb += 32) {
        bf16x8 a0 = *(const bf16x8*)(pa + kb);
        bf16x8 a1 = *(const bf16x8*)(pb + kb);
#pragma unroll
        for (int ct = 0; ct < 8; ++ct) {
            bf16x8 b = *(const bf16x8*)&Ws[ct * 16 + l16][kb + quad * 8];
            acc[0][ct] = __builtin_amdgcn_mfma_f32_16x16x32_bf16(a0, b, acc[0][ct], 0, 0, 0);
            acc[1][ct] = __builtin_amdgcn_mfma_f32_16x16x32_bf16(a1, b, acc[1][ct], 0, 0, 0);
        }
    }

    float bv[8];
#pragma unroll
    for (int ct = 0; ct < 8; ++ct) bv[ct] = bias[ct * 16 + l16];

#pragma unroll
    for (int rt = 0; rt < 2; ++rt) {
#pragma unroll
        for (int r = 0; r < 4; ++r) {
            int row = row0 + rt * 16 + quad * 4 + r;
            if (row >= N_NODES) continue;
#pragma unroll
            for (int ct = 0; ct < 8; ++ct) {
                float v = acc[rt][ct][r] + bv[ct];
                if (RELU) v = fmaxf(v, 0.f);
                int col = ct * 16 + l16;
                if (OUT32) outf[(size_t)row * D + col] = v;
                else outb[(size_t)row * D + col] = f2bf(v);
            }
        }
    }
}

extern "C" void kernel_launch(void* const* d_in, const int* in_sizes, int n_in,
                              void* d_out, int out_size, void* d_ws, size_t ws_size,
                              hipStream_t stream) {
    const int* indices = (const int*)d_in[0];      // [2, E]
    const float* values = (const float*)d_in[1];   // [E]
    const float* features = (const float*)d_in[2]; // [N, 128]
    const float* W1 = (const float*)d_in[3];
    const float* b1 = (const float*)d_in[4];
    const float* W2 = (const float*)d_in[5];
    const float* b2 = (const float*)d_in[6];

    const int* row = indices;
    const int* col = indices + N_EDGES;

    // ws: counts[N] | cursor[N] | offsets[N+1] pad | bsums[256] | scev[E] int2 |
    //     featb/Hb [N*D u16] | W1t[16384] | W2t[16384]   (~39.7 MB total)
    int* wsI = (int*)d_ws;
    int* counts = wsI;
    int* cursor = wsI + N_NODES;
    int* offsets = wsI + 2 * N_NODES;
    int* bsums = wsI + 3 * N_NODES + 8;
    int2* scev = (int2*)(wsI + 3 * N_NODES + 8 + 256);
    u16* featb = (u16*)(scev + N_EDGES);
    u16* Hb = featb;  // reuse: featb dead after spmm
    u16* W1t = featb + (size_t)N_NODES * D;
    u16* W2t = W1t + 16384;

    // combined (bf16) lives in the upper half of d_out; dead before gemm2 writes
    u16* Xb = (u16*)((char*)d_out + (size_t)N_NODES * D * 2);
    float* outf = (float*)d_out;

    hipMemsetAsync(counts, 0, 2 * N_NODES * sizeof(int), stream);

    int eb = (N_EDGES + 255) / 256;  // 6250
    convert_feat<<<N_NODES * D / 8 / 256, 256, 0, stream>>>((const float4*)features, (uint4*)featb);
    convert_w<<<128, 256, 0, stream>>>(W1, W2, W1t, W2t);
    hist_kernel<<<eb, 256, 0, stream>>>(row, counts);
    scan_reduce<<<SCAN_BLOCKS, 256, 0, stream>>>(counts, bsums);
    scan_top<<<1, 256, 0, stream>>>(bsums, SCAN_BLOCKS, offsets);
    scan_apply<<<SCAN_BLOCKS, 256, 0, stream>>>(counts, bsums, offsets);
    scatter_kernel<<<eb, 256, 0, stream>>>(row, col, values, offsets, cursor, scev);

    spmm_bf16<<<(N_NODES * 64 + 255) / 256, 256, 0, stream>>>(scev, offsets, (const u32*)featb,
                                                              (u32*)Xb);

    int gb = (N_NODES + 127) / 128;  // 782
    gemm_mfma<1, 0><<<gb, 256, 0, stream>>>(Xb, W1t, b1, Hb, nullptr);
    gemm_mfma<0, 1><<<gb, 256, 0, stream>>>(Hb, W2t, b2, nullptr, outf);
}

// Round 4
// 377.506 us; speedup vs baseline: 3.6112x; 1.2024x over previous
//
#include <hip/hip_runtime.h>

#define N_NODES 100000
#define N_EDGES 1600000
#define D 128
#define SCAN_CHUNK 1024
#define SCAN_BLOCKS ((N_NODES + SCAN_CHUNK - 1) / SCAN_CHUNK)  // 98

typedef unsigned short u16;
typedef unsigned int u32;
typedef __attribute__((ext_vector_type(8))) short bf16x8;
typedef __attribute__((ext_vector_type(4))) float f32x4;

__device__ __forceinline__ u16 f2bf(float f) {
    u32 u = __float_as_uint(f);
    u += 0x7fffu + ((u >> 16) & 1u);  // round-to-nearest-even
    return (u16)(u >> 16);
}

// ---------------- bf16 conversions ----------------

// features fp32 [N,128] -> bf16 packed. 8 elems/thread. grid = N*D/8/256 = 6250
__global__ void convert_feat(const float4* __restrict__ f4, uint4* __restrict__ o4) {
    int idx = blockIdx.x * blockDim.x + threadIdx.x;  // [0, N*D/8)
    float4 a = f4[idx * 2], b = f4[idx * 2 + 1];
    uint4 o;
    o.x = (u32)f2bf(a.x) | ((u32)f2bf(a.y) << 16);
    o.y = (u32)f2bf(a.z) | ((u32)f2bf(a.w) << 16);
    o.z = (u32)f2bf(b.x) | ((u32)f2bf(b.y) << 16);
    o.w = (u32)f2bf(b.z) | ((u32)f2bf(b.w) << 16);
    o4[idx] = o;
}

// W[k][n] fp32 -> Wt[n][k] bf16, both 128x128. grid = 2*16384/256 = 128
__global__ void convert_w(const float* __restrict__ W1, const float* __restrict__ W2,
                          u16* __restrict__ W1t, u16* __restrict__ W2t) {
    int flat = blockIdx.x * blockDim.x + threadIdx.x;  // [0, 32768)
    int m = flat >> 14;
    int idx = flat & 16383;
    int n = idx & 127;   // consecutive threads -> consecutive n: coalesced read
    int k = idx >> 7;
    const float* src = m ? W2 : W1;
    u16* dst = m ? W2t : W1t;
    dst[n * 128 + k] = f2bf(src[k * 128 + n]);
}

// ---------------- CSR build ----------------

__global__ void hist_kernel(const int* __restrict__ row, int* __restrict__ counts) {
    int e = blockIdx.x * blockDim.x + threadIdx.x;
    if (e < N_EDGES) atomicAdd(&counts[row[e]], 1);
}

__global__ void scan_reduce(const int* __restrict__ counts, int* __restrict__ bsums) {
    int b = blockIdx.x, t = threadIdx.x;
    int base = b * SCAN_CHUNK + t * 4;
    int s = 0;
#pragma unroll
    for (int i = 0; i < 4; ++i) {
        int idx = base + i;
        if (idx < N_NODES) s += counts[idx];
    }
    __shared__ int red[256];
    red[t] = s;
    __syncthreads();
    for (int d = 128; d > 0; d >>= 1) {
        if (t < d) red[t] += red[t + d];
        __syncthreads();
    }
    if (t == 0) bsums[b] = red[0];
}

__global__ void scan_top(int* __restrict__ bsums, int nb, int* __restrict__ offsets) {
    __shared__ int s[256];
    int t = threadIdx.x;
    int v = (t < nb) ? bsums[t] : 0;
    s[t] = v;
    __syncthreads();
    for (int d = 1; d < 256; d <<= 1) {
        int x = (t >= d) ? s[t - d] : 0;
        __syncthreads();
        s[t] += x;
        __syncthreads();
    }
    if (t < nb) bsums[t] = s[t] - v;  // exclusive
    if (t == 0) offsets[N_NODES] = N_EDGES;
}

__global__ void scan_apply(const int* __restrict__ counts, const int* __restrict__ bsums,
                           int* __restrict__ offsets) {
    int b = blockIdx.x, t = threadIdx.x;
    int base = b * SCAN_CHUNK + t * 4;
    int c[4];
    int s = 0;
#pragma unroll
    for (int i = 0; i < 4; ++i) {
        int idx = base + i;
        c[i] = (idx < N_NODES) ? counts[idx] : 0;
        s += c[i];
    }
    __shared__ int sc[256];
    int mine = s;
    sc[t] = s;
    __syncthreads();
    for (int d = 1; d < 256; d <<= 1) {
        int x = (t >= d) ? sc[t - d] : 0;
        __syncthreads();
        sc[t] += x;
        __syncthreads();
    }
    int run = sc[t] - mine + bsums[b];
#pragma unroll
    for (int i = 0; i < 4; ++i) {
        int idx = base + i;
        if (idx < N_NODES) offsets[idx] = run;
        run += c[i];
    }
}

// packed (col, val) per edge: one 8B store instead of two 4B stores
__global__ void scatter_kernel(const int* __restrict__ row, const int* __restrict__ col,
                               const float* __restrict__ val, const int* __restrict__ offsets,
                               int* __restrict__ cursor, int2* __restrict__ scev) {
    int e = blockIdx.x * blockDim.x + threadIdx.x;
    if (e >= N_EDGES) return;
    int r = row[e];
    int p = offsets[r] + atomicAdd(&cursor[r], 1);
    int2 ev;
    ev.x = col[e];
    ev.y = __float_as_int(val[e]);
    scev[p] = ev;
}

// ---------------- SpMM (bf16 gather): one wave per row ----------------
// Xb[r] = bf16( featb[r] + sum_j v_j * featb[col_j] )
// wid forced wave-uniform via readfirstlane -> offsets/scev become scalar
// loads (s_load_dwordx16 grabs 8 edges); unroll x8 puts 8 independent
// 256B gathers in flight per wave to cover ~600-900cy LLC latency.

__global__ __launch_bounds__(256) void spmm_bf16(
    const int2* __restrict__ scev, const int* __restrict__ offsets,
    const u32* __restrict__ featb, u32* __restrict__ Xb) {
    int wid0 = (blockIdx.x * blockDim.x + threadIdx.x) >> 6;
    int wid = __builtin_amdgcn_readfirstlane(wid0);
    int lane = threadIdx.x & 63;
    if (wid >= N_NODES) return;
    int beg = offsets[wid], end = offsets[wid + 1];
    u32 self = featb[wid * 64 + lane];
    float ax0 = __uint_as_float(self << 16);
    float ay0 = __uint_as_float(self & 0xffff0000u);
    float ax1 = 0.f, ay1 = 0.f;
    int j = beg;
    for (; j + 8 <= end; j += 8) {
        int2 e[8];
        u32 p[8];
#pragma unroll
        for (int u = 0; u < 8; ++u) e[u] = scev[j + u];
#pragma unroll
        for (int u = 0; u < 8; ++u) p[u] = featb[e[u].x * 64 + lane];
#pragma unroll
        for (int u = 0; u < 8; ++u) {
            float v = __int_as_float(e[u].y);
            float lo = __uint_as_float(p[u] << 16);
            float hi = __uint_as_float(p[u] & 0xffff0000u);
            if (u & 1) {
                ax1 += v * lo;
                ay1 += v * hi;
            } else {
                ax0 += v * lo;
                ay0 += v * hi;
            }
        }
    }
    for (; j < end; ++j) {
        int2 e = scev[j];
        float v = __int_as_float(e.y);
        u32 p = featb[e.x * 64 + lane];
        ax0 += v * __uint_as_float(p << 16);
        ay0 += v * __uint_as_float(p & 0xffff0000u);
    }
    float accx = ax0 + ax1;
    float accy = ay0 + ay1;
    Xb[wid * 64 + lane] = (u32)f2bf(accx) | ((u32)f2bf(accy) << 16);
}

// ---------------- MFMA bf16 GEMM: out = act(X @ W + b) ----------------
// Block 256 = 4 waves; block tile 128 rows; wave tile 32 rows x 128 cols.
// Wt[n][k] staged in LDS (pad 136 -> 2-way conflicts = free).
// A-fragments loaded straight from global (16 rows x 64B: fully coalesced).
// mfma_f32_16x16x32_bf16: A lane=(m=l&15, k=quad*8+j); B lane=(n=l&15, k=quad*8+j);
// D lane: col=l&15, row=quad*4+reg  [guide §3, m89/m91-verified]

template <int RELU, int OUT32>
__global__ __launch_bounds__(256, 2) void gemm_mfma(
    const u16* __restrict__ Xb, const u16* __restrict__ Wt,
    const float* __restrict__ bias, u16* __restrict__ outb, float* __restrict__ outf) {
    __shared__ u16 Ws[128][136];
    int t = threadIdx.x;
    {
        const uint4* wsrc = (const uint4*)Wt;
#pragma unroll
        for (int i = 0; i < 8; ++i) {
            int f = t + 256 * i;  // [0,2048) 16B chunks
            int n = f >> 4;
            int c8 = (f & 15) << 3;
            *(uint4*)&Ws[n][c8] = wsrc[f];
        }
    }
    __syncthreads();

    int w = t >> 6, lane = t & 63;
    int quad = lane >> 4, l16 = lane & 15;
    int row0 = blockIdx.x * 128 + w * 32;

    f32x4 acc[2][8];
#pragma unroll
    for (int rt = 0; rt < 2; ++rt)
#pragma unroll
        for (int ct = 0; ct < 8; ++ct) acc[rt][ct] = (f32x4){0.f, 0.f, 0.f, 0.f};

    int ra = row0 + l16;
    int rb = row0 + 16 + l16;
    if (ra > N_NODES - 1) ra = N_NODES - 1;  // clamp: keeps loads in-bounds,
    if (rb > N_NODES - 1) rb = N_NODES - 1;  // stores are guarded below
    const u16* pa = Xb + (size_t)ra * D + quad * 8;
    const u16* pb = Xb + (size_t)rb * D + quad * 8;

#pragma unroll
    for (int kb = 0; kb < 128; kb += 32) {
        bf16x8 a0 = *(const bf16x8*)(pa + kb);
        bf16x8 a1 = *(const bf16x8*)(pb + kb);
#pragma unroll
        for (int ct = 0; ct < 8; ++ct) {
            bf16x8 b = *(const bf16x8*)&Ws[ct * 16 + l16][kb + quad * 8];
            acc[0][ct] = __builtin_amdgcn_mfma_f32_16x16x32_bf16(a0, b, acc[0][ct], 0, 0, 0);
            acc[1][ct] = __builtin_amdgcn_mfma_f32_16x16x32_bf16(a1, b, acc[1][ct], 0, 0, 0);
        }
    }

    float bv[8];
#pragma unroll
    for (int ct = 0; ct < 8; ++ct) bv[ct] = bias[ct * 16 + l16];

#pragma unroll
    for (int rt = 0; rt < 2; ++rt) {
#pragma unroll
        for (int r = 0; r < 4; ++r) {
            int row = row0 + rt * 16 + quad * 4 + r;
            if (row >= N_NODES) continue;
#pragma unroll
            for (int ct = 0; ct < 8; ++ct) {
                float v = acc[rt][ct][r] + bv[ct];
                if (RELU) v = fmaxf(v, 0.f);
                int col = ct * 16 + l16;
                if (OUT32) outf[(size_t)row * D + col] = v;
                else outb[(size_t)row * D + col] = f2bf(v);
            }
        }
    }
}

extern "C" void kernel_launch(void* const* d_in, const int* in_sizes, int n_in,
                              void* d_out, int out_size, void* d_ws, size_t ws_size,
                              hipStream_t stream) {
    const int* indices = (const int*)d_in[0];      // [2, E]
    const float* values = (const float*)d_in[1];   // [E]
    const float* features = (const float*)d_in[2]; // [N, 128]
    const float* W1 = (const float*)d_in[3];
    const float* b1 = (const float*)d_in[4];
    const float* W2 = (const float*)d_in[5];
    const float* b2 = (const float*)d_in[6];

    const int* row = indices;
    const int* col = indices + N_EDGES;

    // ws: counts[N] | cursor[N] | offsets[N+1] pad | bsums[256] | scev[E] int2 |
    //     featb/Hb [N*D u16] | W1t[16384] | W2t[16384]   (~39.7 MB total)
    int* wsI = (int*)d_ws;
    int* counts = wsI;
    int* cursor = wsI + N_NODES;
    int* offsets = wsI + 2 * N_NODES;
    int* bsums = wsI + 3 * N_NODES + 8;
    int2* scev = (int2*)(wsI + 3 * N_NODES + 8 + 256);
    u16* featb = (u16*)(scev + N_EDGES);
    u16* Hb = featb;  // reuse: featb dead after spmm
    u16* W1t = featb + (size_t)N_NODES * D;
    u16* W2t = W1t + 16384;

    // combined (bf16) lives in the upper half of d_out; dead before gemm2 writes
    u16* Xb = (u16*)((char*)d_out + (size_t)N_NODES * D * 2);
    float* outf = (float*)d_out;

    hipMemsetAsync(counts, 0, 2 * N_NODES * sizeof(int), stream);

    int eb = (N_EDGES + 255) / 256;  // 6250
    convert_feat<<<N_NODES * D / 8 / 256, 256, 0, stream>>>((const float4*)features, (uint4*)featb);
    convert_w<<<128, 256, 0, stream>>>(W1, W2, W1t, W2t);
    hist_kernel<<<eb, 256, 0, stream>>>(row, counts);
    scan_reduce<<<SCAN_BLOCKS, 256, 0, stream>>>(counts, bsums);
    scan_top<<<1, 256, 0, stream>>>(bsums, SCAN_BLOCKS, offsets);
    scan_apply<<<SCAN_BLOCKS, 256, 0, stream>>>(counts, bsums, offsets);
    scatter_kernel<<<eb, 256, 0, stream>>>(row, col, values, offsets, cursor, scev);

    spmm_bf16<<<(N_NODES * 64 + 255) / 256, 256, 0, stream>>>(scev, offsets, (const u32*)featb,
                                                              (u32*)Xb);

    int gb = (N_NODES + 127) / 128;  // 782
    gemm_mfma<1, 0><<<gb, 256, 0, stream>>>(Xb, W1t, b1, Hb, nullptr);
    gemm_mfma<0, 1><<<gb, 256, 0, stream>>>(Hb, W2t, b2, nullptr, outf);
}

// Round 5
// 312.587 us; speedup vs baseline: 4.3612x; 1.2077x over previous
//
#include <hip/hip_runtime.h>

#define N_NODES 100000
#define N_EDGES 1600000
#define D 128
#define NB 782  // ceil(N_NODES/128) buckets of 128 rows

typedef unsigned short u16;
typedef unsigned int u32;
typedef __attribute__((ext_vector_type(8))) short bf16x8;
typedef __attribute__((ext_vector_type(4))) float f32x4;

__device__ __forceinline__ u16 f2bf(float f) {
    u32 u = __float_as_uint(f);
    u += 0x7fffu + ((u >> 16) & 1u);  // round-to-nearest-even
    return (u16)(u >> 16);
}

// ---------------- bf16 conversions ----------------

__global__ void convert_feat(const float4* __restrict__ f4, uint4* __restrict__ o4) {
    int idx = blockIdx.x * blockDim.x + threadIdx.x;  // [0, N*D/8)
    float4 a = f4[idx * 2], b = f4[idx * 2 + 1];
    uint4 o;
    o.x = (u32)f2bf(a.x) | ((u32)f2bf(a.y) << 16);
    o.y = (u32)f2bf(a.z) | ((u32)f2bf(a.w) << 16);
    o.z = (u32)f2bf(b.x) | ((u32)f2bf(b.y) << 16);
    o.w = (u32)f2bf(b.z) | ((u32)f2bf(b.w) << 16);
    o4[idx] = o;
}

__global__ void convert_w(const float* __restrict__ W1, const float* __restrict__ W2,
                          u16* __restrict__ W1t, u16* __restrict__ W2t) {
    int flat = blockIdx.x * blockDim.x + threadIdx.x;  // [0, 32768)
    int m = flat >> 14;
    int idx = flat & 16383;
    int n = idx & 127;
    int k = idx >> 7;
    const float* src = m ? W2 : W1;
    u16* dst = m ? W2t : W1t;
    dst[n * 128 + k] = f2bf(src[k * 128 + n]);
}

// ---------------- bucketed CSR build ----------------
// bucket = row >> 7 (128 rows/bucket). Edges first appended bucket-grouped
// (bin_pass), then exact-sorted within each bucket by a single block
// (bucket_sort) which also derives the per-row CSR offsets -> no global
// row-granular histogram/scan needed at all.

__global__ __launch_bounds__(256) void bucket_hist(const int* __restrict__ row,
                                                   int* __restrict__ bhist) {
    __shared__ int h[NB];
    int t = threadIdx.x;
    for (int i = t; i < NB; i += 256) h[i] = 0;
    __syncthreads();
    int base = blockIdx.x * 4096 + t;
#pragma unroll
    for (int i = 0; i < 16; ++i) {
        int e = base + i * 256;
        if (e < N_EDGES) atomicAdd(&h[row[e] >> 7], 1);
    }
    __syncthreads();
    for (int i = t; i < NB; i += 256) {
        int c = h[i];
        if (c) atomicAdd(&bhist[i], c);
    }
}

__global__ void bucket_scan(const int* __restrict__ bhist, int* __restrict__ bucketOff,
                            int* __restrict__ bucketCursor) {
    __shared__ int part[256];
    int t = threadIdx.x;
    int v[4];
    int s = 0;
#pragma unroll
    for (int i = 0; i < 4; ++i) {
        int idx = t * 4 + i;
        v[i] = (idx < NB) ? bhist[idx] : 0;
        s += v[i];
    }
    int mine = s;
    part[t] = s;
    __syncthreads();
    for (int d = 1; d < 256; d <<= 1) {
        int x = (t >= d) ? part[t - d] : 0;
        __syncthreads();
        part[t] += x;
        __syncthreads();
    }
    int run = part[t] - mine;  // exclusive base
#pragma unroll
    for (int i = 0; i < 4; ++i) {
        int idx = t * 4 + i;
        if (idx < NB) {
            bucketOff[idx] = run;
            bucketCursor[idx] = run;
        }
        run += v[i];
    }
    if (t == 0) bucketOff[NB] = N_EDGES;
}

// append edges grouped by bucket; pack row-local (7b) into col's high bits
__global__ __launch_bounds__(256) void bin_pass(const int* __restrict__ row,
                                                const int* __restrict__ col,
                                                const float* __restrict__ val,
                                                int* __restrict__ bucketCursor,
                                                int2* __restrict__ binned) {
    __shared__ int hist[NB];
    __shared__ int lbase[NB];
    int t = threadIdx.x;
    for (int i = t; i < NB; i += 256) hist[i] = 0;
    __syncthreads();
    int base = blockIdx.x * 4096;
    int r[16];
#pragma unroll
    for (int i = 0; i < 16; ++i) {
        int e = base + i * 256 + t;
        r[i] = (e < N_EDGES) ? row[e] : -1;
        if (r[i] >= 0) atomicAdd(&hist[r[i] >> 7], 1);
    }
    __syncthreads();
    for (int i = t; i < NB; i += 256) {
        int c = hist[i];
        lbase[i] = c ? atomicAdd(&bucketCursor[i], c) : 0;
    }
    __syncthreads();
    for (int i = t; i < NB; i += 256) hist[i] = 0;  // reuse as local cursor
    __syncthreads();
#pragma unroll
    for (int i = 0; i < 16; ++i) {
        if (r[i] < 0) continue;
        int e = base + i * 256 + t;
        int bkt = r[i] >> 7;
        int pos = lbase[bkt] + atomicAdd(&hist[bkt], 1);
        int2 ev;
        ev.x = col[e] | ((r[i] & 127) << 17);  // col < 2^17
        ev.y = __float_as_int(val[e]);
        binned[pos] = ev;
    }
}

// one block per bucket: derive per-row offsets (writes CSR offsets) and
// scatter edges into exact sorted position. All writes land in the bucket's
// own ~16KB window -> full-line, single-XCD locality.
__global__ __launch_bounds__(256) void bucket_sort(const int2* __restrict__ binned,
                                                   const int* __restrict__ bucketOff,
                                                   int* __restrict__ offsets,
                                                   int2* __restrict__ scev) {
    __shared__ int h[128];
    __shared__ int cur[128];
    int b = blockIdx.x, t = threadIdx.x;
    int row0 = b << 7;
    int nrows = N_NODES - row0;
    if (nrows > 128) nrows = 128;
    if (t < 128) h[t] = 0;
    __syncthreads();
    int lo = bucketOff[b], hi = bucketOff[b + 1];
    for (int i = lo + t; i < hi; i += 256)
        atomicAdd(&h[((u32)binned[i].x) >> 17], 1);
    __syncthreads();
    if (t < 128) cur[t] = h[t];
    __syncthreads();
    for (int d = 1; d < 128; d <<= 1) {
        int x = 0;
        if (t < 128 && t >= d) x = cur[t - d];
        __syncthreads();
        if (t < 128) cur[t] += x;
        __syncthreads();
    }
    if (t < 128) {
        int excl = lo + cur[t] - h[t];
        if (t < nrows) offsets[row0 + t] = excl;
        cur[t] = excl;  // per-row cursor
    }
    __syncthreads();
    for (int i = lo + t; i < hi; i += 256) {
        int2 ev = binned[i];
        int rl = ((u32)ev.x) >> 17;
        int pos = atomicAdd(&cur[rl], 1);
        scev[pos] = make_int2(ev.x & 0x1FFFF, ev.y);
    }
    if (b == 0 && t == 0) offsets[N_NODES] = N_EDGES;
}

// ---------------- SpMM (bf16 gather): one wave per row ----------------

__global__ __launch_bounds__(256) void spmm_bf16(
    const int2* __restrict__ scev, const int* __restrict__ offsets,
    const u32* __restrict__ featb, u32* __restrict__ Xb) {
    int wid0 = (blockIdx.x * blockDim.x + threadIdx.x) >> 6;
    int wid = __builtin_amdgcn_readfirstlane(wid0);
    int lane = threadIdx.x & 63;
    if (wid >= N_NODES) return;
    int beg = offsets[wid], end = offsets[wid + 1];
    u32 self = featb[wid * 64 + lane];
    float ax0 = __uint_as_float(self << 16);
    float ay0 = __uint_as_float(self & 0xffff0000u);
    float ax1 = 0.f, ay1 = 0.f;
    int j = beg;
    for (; j + 8 <= end; j += 8) {
        int2 e[8];
        u32 p[8];
#pragma unroll
        for (int u = 0; u < 8; ++u) e[u] = scev[j + u];
#pragma unroll
        for (int u = 0; u < 8; ++u) p[u] = featb[e[u].x * 64 + lane];
#pragma unroll
        for (int u = 0; u < 8; ++u) {
            float v = __int_as_float(e[u].y);
            float lo = __uint_as_float(p[u] << 16);
            float hi = __uint_as_float(p[u] & 0xffff0000u);
            if (u & 1) {
                ax1 += v * lo;
                ay1 += v * hi;
            } else {
                ax0 += v * lo;
                ay0 += v * hi;
            }
        }
    }
    for (; j < end; ++j) {
        int2 e = scev[j];
        float v = __int_as_float(e.y);
        u32 p = featb[e.x * 64 + lane];
        ax0 += v * __uint_as_float(p << 16);
        ay0 += v * __uint_as_float(p & 0xffff0000u);
    }
    float accx = ax0 + ax1;
    float accy = ay0 + ay1;
    Xb[wid * 64 + lane] = (u32)f2bf(accx) | ((u32)f2bf(accy) << 16);
}

// ---------------- MFMA bf16 GEMM: out = act(X @ W + b) ----------------

template <int RELU, int OUT32>
__global__ __launch_bounds__(256, 2) void gemm_mfma(
    const u16* __restrict__ Xb, const u16* __restrict__ Wt,
    const float* __restrict__ bias, u16* __restrict__ outb, float* __restrict__ outf) {
    __shared__ u16 Ws[128][136];
    int t = threadIdx.x;
    {
        const uint4* wsrc = (const uint4*)Wt;
#pragma unroll
        for (int i = 0; i < 8; ++i) {
            int f = t + 256 * i;
            int n = f >> 4;
            int c8 = (f & 15) << 3;
            *(uint4*)&Ws[n][c8] = wsrc[f];
        }
    }
    __syncthreads();

    int w = t >> 6, lane = t & 63;
    int quad = lane >> 4, l16 = lane & 15;
    int row0 = blockIdx.x * 128 + w * 32;

    f32x4 acc[2][8];
#pragma unroll
    for (int rt = 0; rt < 2; ++rt)
#pragma unroll
        for (int ct = 0; ct < 8; ++ct) acc[rt][ct] = (f32x4){0.f, 0.f, 0.f, 0.f};

    int ra = row0 + l16;
    int rb = row0 + 16 + l16;
    if (ra > N_NODES - 1) ra = N_NODES - 1;
    if (rb > N_NODES - 1) rb = N_NODES - 1;
    const u16* pa = Xb + (size_t)ra * D + quad * 8;
    const u16* pb = Xb + (size_t)rb * D + quad * 8;

#pragma unroll
    for (int kb = 0; kb < 128; kb += 32) {
        bf16x8 a0 = *(const bf16x8*)(pa + kb);
        bf16x8 a1 = *(const bf16x8*)(pb + kb);
#pragma unroll
        for (int ct = 0; ct < 8; ++ct) {
            bf16x8 b = *(const bf16x8*)&Ws[ct * 16 + l16][kb + quad * 8];
            acc[0][ct] = __builtin_amdgcn_mfma_f32_16x16x32_bf16(a0, b, acc[0][ct], 0, 0, 0);
            acc[1][ct] = __builtin_amdgcn_mfma_f32_16x16x32_bf16(a1, b, acc[1][ct], 0, 0, 0);
        }
    }

    float bv[8];
#pragma unroll
    for (int ct = 0; ct < 8; ++ct) bv[ct] = bias[ct * 16 + l16];

#pragma unroll
    for (int rt = 0; rt < 2; ++rt) {
#pragma unroll
        for (int r = 0; r < 4; ++r) {
            int row = row0 + rt * 16 + quad * 4 + r;
            if (row >= N_NODES) continue;
#pragma unroll
            for (int ct = 0; ct < 8; ++ct) {
                float v = acc[rt][ct][r] + bv[ct];
                if (RELU) v = fmaxf(v, 0.f);
                int col = ct * 16 + l16;
                if (OUT32) outf[(size_t)row * D + col] = v;
                else outb[(size_t)row * D + col] = f2bf(v);
            }
        }
    }
}

extern "C" void kernel_launch(void* const* d_in, const int* in_sizes, int n_in,
                              void* d_out, int out_size, void* d_ws, size_t ws_size,
                              hipStream_t stream) {
    const int* indices = (const int*)d_in[0];      // [2, E]
    const float* values = (const float*)d_in[1];   // [E]
    const float* features = (const float*)d_in[2]; // [N, 128]
    const float* W1 = (const float*)d_in[3];
    const float* b1 = (const float*)d_in[4];
    const float* W2 = (const float*)d_in[5];
    const float* b2 = (const float*)d_in[6];

    const int* row = indices;
    const int* col = indices + N_EDGES;

    // ws: offsets[N+1] pad | bhist[NB] | bucketOff[NB+1] | bucketCursor[NB] pad |
    //     scev[E] int2 | featb/Hb [N*D u16] | W1t | W2t   (~39 MB)
    int* wsI = (int*)d_ws;
    int* offsets = wsI;
    int* bhist = wsI + N_NODES + 8;
    int* bucketOff = bhist + NB;
    int* bucketCursor = bucketOff + NB + 1;
    int2* scev = (int2*)(bucketCursor + NB + 7);
    u16* featb = (u16*)(scev + N_EDGES);
    u16* Hb = featb;  // reuse: featb dead after spmm
    u16* W1t = featb + (size_t)N_NODES * D;
    u16* W2t = W1t + 16384;

    // d_out: binned[E] int2 in lower half (dead before gemm2 writes);
    // Xb (combined bf16) in upper half (dead after gemm1)
    int2* binned = (int2*)d_out;
    u16* Xb = (u16*)((char*)d_out + (size_t)N_NODES * D * 2);
    float* outf = (float*)d_out;

    hipMemsetAsync(bhist, 0, NB * sizeof(int), stream);

    convert_feat<<<N_NODES * D / 8 / 256, 256, 0, stream>>>((const float4*)features, (uint4*)featb);
    convert_w<<<128, 256, 0, stream>>>(W1, W2, W1t, W2t);

    int cb = (N_EDGES + 4095) / 4096;  // 391
    bucket_hist<<<cb, 256, 0, stream>>>(row, bhist);
    bucket_scan<<<1, 256, 0, stream>>>(bhist, bucketOff, bucketCursor);
    bin_pass<<<cb, 256, 0, stream>>>(row, col, values, bucketCursor, binned);
    bucket_sort<<<NB, 256, 0, stream>>>(binned, bucketOff, offsets, scev);

    spmm_bf16<<<(N_NODES * 64 + 255) / 256, 256, 0, stream>>>(scev, offsets, (const u32*)featb,
                                                              (u32*)Xb);

    int gb = (N_NODES + 127) / 128;  // 782
    gemm_mfma<1, 0><<<gb, 256, 0, stream>>>(Xb, W1t, b1, Hb, nullptr);
    gemm_mfma<0, 1><<<gb, 256, 0, stream>>>(Hb, W2t, b2, nullptr, outf);
}